// Round 13
// baseline (720.681 us; speedup 1.0000x reference)
//
#include <hip/hip_runtime.h>

// Problem constants
#define K_CODES 512
#define DIM 80
#define SEQ 4096
#define NVEC 131072
#define NELEM ((size_t)NVEC * DIM)
#define NQ 4                         // code quarters (BN=128)
#define MCHUNK 512                   // vectors per block
#define ITERS 4                      // per wave: 4 iterations x 32 vectors
#define QBYTES 49152                 // 8 groups x 6 frags x 64 lanes x 16B

typedef short short8 __attribute__((ext_vector_type(8)));
typedef float f32x4 __attribute__((ext_vector_type(4)));

// ws layout: ghist[512] @0 | gsq @2048 | wsq[512] @4096 | wfrag @8192 (196608 B)
//            | pd float[4][NVEC] @204800 | pk u8[4][NVEC] @2301952
#define WS_GSQ   2048
#define WS_WSQ   4096
#define WS_WFRAG 8192
#define WS_PD    204800
#define WS_PK    (204800 + 4 * NVEC * 4)

__device__ __forceinline__ unsigned short f2bf(float f) {
    union { float f; unsigned int u; } c; c.f = f;
    unsigned int r = c.u + 0x7FFFu + ((c.u >> 16) & 1u);   // RNE
    return (unsigned short)(r >> 16);
}
__device__ __forceinline__ float bf2f(unsigned short h) {
    union { float f; unsigned int u; } c; c.u = ((unsigned int)h) << 16;
    return c.f;
}

__device__ __forceinline__ void gload_lds16(const void* g, void* l) {
    __builtin_amdgcn_global_load_lds(
        (const __attribute__((address_space(1))) void*)g,
        (__attribute__((address_space(3))) void*)l, 16, 0, 0);
}

// Fused setup: wfrag (fragment-ordered split codebook) + wsq (row norms).
// wfrag: [t16 0..31][g 0..5][lane 0..63] short8; g<3: hi,ks=g; g>=3: lo,ks=g-3;
//        lane=(cg<<4)|cl; value = w{hi,lo}[code=t16*16+cl][c=ks*32+cg*8 ..+8)
// Quarter q = 16-code tiles [8q, 8q+8) = bytes [q*49152, +49152).
__global__ void vq_setup(const float* __restrict__ weight,
                         short8* __restrict__ wf, float* __restrict__ wsq)
{
    int idx = blockIdx.x * 256 + threadIdx.x;   // 48 blocks -> 12288
    if (blockIdx.x < 2) {
        int k = blockIdx.x * 256 + threadIdx.x;
        const float* w = weight + (size_t)k * DIM;
        float s = 0.f;
#pragma unroll
        for (int c = 0; c < DIM; ++c) s = fmaf(w[c], w[c], s);
        wsq[k] = s;
    }
    int t   = idx / 384;
    int rem = idx - t * 384;
    int g   = rem >> 6, l = rem & 63;
    int cl  = l & 15, cg = l >> 4;
    int ks  = g % 3, h = g / 3;
    int code = t * 16 + cl;
    int c0 = ks * 32 + cg * 8;
    short8 v;
#pragma unroll
    for (int j = 0; j < 8; ++j) {
        int c = c0 + j;
        unsigned short r = 0;
        if (c < DIM) {
            float f = weight[(size_t)code * DIM + c];
            unsigned short hb = f2bf(f);
            r = h ? f2bf(f - bf2f(hb)) : hb;
        }
        v[j] = (short)r;
    }
    wf[idx] = v;
}

// Barrier-free quarter-GEMM argmin. Block = [512 vectors] x [128 codes of
// quarter q]. B-quarter (48 KB) staged to LDS ONCE; then each wave sweeps
// 4 x 32 vectors independently: 8 groups x {6 ds_read_b128 + 18 MFMA + fold}.
// Partial (d, k_local) per vector written to ws; merged in the epilogue.
__global__ __launch_bounds__(256, 3) void vq_argmin(
    const float* __restrict__ x, const short8* __restrict__ wf,
    const float* __restrict__ wsq,
    float* __restrict__ pd, unsigned char* __restrict__ pk)
{
    __shared__ short8 blds[3072];   // 49152 B: [g 0..7][frag 0..5][lane 0..63]

    const int tid = threadIdx.x;
    const int q      = blockIdx.x >> 8;     // quarter (q-major: wfrag L2-hot)
    const int mchunk = blockIdx.x & 255;
    const int v0 = mchunk * MCHUNK;
    const int b  = v0 >> 12;                // 512 | 4096 -> whole block same b
    const int l0 = v0 & 4095;
    const float* xbase = x + (size_t)b * DIM * SEQ + l0;

    const int lane = tid & 63, wid = tid >> 6;
    const int cg = lane >> 4;          // k-group 0..3
    const int cl = lane & 15;          // A row / B col

    // ---- stage B-quarter: 12 linear gload_lds16 per thread ----
    {
        const char* src = (const char*)wf + (size_t)q * QBYTES + tid * 16;
        char* dst = (char*)&blds[0] + tid * 16;
#pragma unroll
        for (int i = 0; i < 12; ++i)
            gload_lds16(src + i * 4096, dst + i * 4096);
    }

    // per-lane code norms for the 8 groups (held in VGPRs)
    float wsqr[8];
#pragma unroll
    for (int g = 0; g < 8; ++g) wsqr[g] = wsq[q * 128 + g * 16 + cl];

    __syncthreads();   // B-quarter staged (drains vmcnt)

    for (int it = 0; it < ITERS; ++it) {
        const int ar0 = wid * 128 + it * 32 + cl;   // set-0 local vector
        const int ar1 = ar0 + 16;                   // set-1

        // ---- A fragments (2 sets, hi/lo), direct from global ----
        short8 ahi0[3], alo0[3], ahi1[3], alo1[3];
#pragma unroll
        for (int ks = 0; ks < 3; ++ks) {
#pragma unroll
            for (int j = 0; j < 8; ++j) {
                int c = ks * 32 + cg * 8 + j;
                unsigned short h0 = 0, p0 = 0, h1 = 0, p1 = 0;
                if (c < DIM) {
                    float f0 = xbase[(size_t)c * SEQ + ar0];
                    float f1 = xbase[(size_t)c * SEQ + ar1];
                    h0 = f2bf(f0); p0 = f2bf(f0 - bf2f(h0));
                    h1 = f2bf(f1); p1 = f2bf(f1 - bf2f(h1));
                }
                ahi0[ks][j] = (short)h0; alo0[ks][j] = (short)p0;
                ahi1[ks][j] = (short)h1; alo1[ks][j] = (short)p1;
            }
        }

        float bestd[2][4];
        int   bestk[2][4];
#pragma unroll
        for (int s = 0; s < 2; ++s)
#pragma unroll
            for (int r = 0; r < 4; ++r) { bestd[s][r] = 3.4028235e38f; bestk[s][r] = 0; }

#pragma unroll
        for (int g = 0; g < 8; ++g) {
            const short8* bb = &blds[g * 384];
            short8 bh0 = bb[lane];
            short8 bh1 = bb[64 + lane];
            short8 bh2 = bb[128 + lane];
            short8 bl0 = bb[192 + lane];
            short8 bl1 = bb[256 + lane];
            short8 bl2 = bb[320 + lane];

            f32x4 a00 = {0.f,0.f,0.f,0.f}, a01 = {0.f,0.f,0.f,0.f}, a02 = {0.f,0.f,0.f,0.f};
            f32x4 a10 = {0.f,0.f,0.f,0.f}, a11 = {0.f,0.f,0.f,0.f}, a12 = {0.f,0.f,0.f,0.f};
            __builtin_amdgcn_s_setprio(1);
            // per chain (set s, ks j): hh(j) -> hl(j) -> lh(j)  (R9-identical)
            a00 = __builtin_amdgcn_mfma_f32_16x16x32_bf16(ahi0[0], bh0, a00, 0, 0, 0);
            a01 = __builtin_amdgcn_mfma_f32_16x16x32_bf16(ahi0[1], bh1, a01, 0, 0, 0);
            a02 = __builtin_amdgcn_mfma_f32_16x16x32_bf16(ahi0[2], bh2, a02, 0, 0, 0);
            a10 = __builtin_amdgcn_mfma_f32_16x16x32_bf16(ahi1[0], bh0, a10, 0, 0, 0);
            a11 = __builtin_amdgcn_mfma_f32_16x16x32_bf16(ahi1[1], bh1, a11, 0, 0, 0);
            a12 = __builtin_amdgcn_mfma_f32_16x16x32_bf16(ahi1[2], bh2, a12, 0, 0, 0);
            a00 = __builtin_amdgcn_mfma_f32_16x16x32_bf16(ahi0[0], bl0, a00, 0, 0, 0);
            a01 = __builtin_amdgcn_mfma_f32_16x16x32_bf16(ahi0[1], bl1, a01, 0, 0, 0);
            a02 = __builtin_amdgcn_mfma_f32_16x16x32_bf16(ahi0[2], bl2, a02, 0, 0, 0);
            a10 = __builtin_amdgcn_mfma_f32_16x16x32_bf16(ahi1[0], bl0, a10, 0, 0, 0);
            a11 = __builtin_amdgcn_mfma_f32_16x16x32_bf16(ahi1[1], bl1, a11, 0, 0, 0);
            a12 = __builtin_amdgcn_mfma_f32_16x16x32_bf16(ahi1[2], bl2, a12, 0, 0, 0);
            a00 = __builtin_amdgcn_mfma_f32_16x16x32_bf16(alo0[0], bh0, a00, 0, 0, 0);
            a01 = __builtin_amdgcn_mfma_f32_16x16x32_bf16(alo0[1], bh1, a01, 0, 0, 0);
            a02 = __builtin_amdgcn_mfma_f32_16x16x32_bf16(alo0[2], bh2, a02, 0, 0, 0);
            a10 = __builtin_amdgcn_mfma_f32_16x16x32_bf16(alo1[0], bh0, a10, 0, 0, 0);
            a11 = __builtin_amdgcn_mfma_f32_16x16x32_bf16(alo1[1], bh1, a11, 0, 0, 0);
            a12 = __builtin_amdgcn_mfma_f32_16x16x32_bf16(alo1[2], bh2, a12, 0, 0, 0);
            __builtin_amdgcn_s_setprio(0);

            const int kloc = g * 16 + cl;
            const float wv = wsqr[g];
#pragma unroll
            for (int r = 0; r < 4; ++r) {
                float d0 = a00[r] + a01[r] + a02[r];
                float q0 = fmaf(-2.f, d0, wv);
                if (q0 < bestd[0][r]) { bestd[0][r] = q0; bestk[0][r] = kloc; }
                float d1 = a10[r] + a11[r] + a12[r];
                float q1 = fmaf(-2.f, d1, wv);
                if (q1 < bestd[1][r]) { bestd[1][r] = q1; bestk[1][r] = kloc; }
            }
        }

        // ---- cross-lane argmin over the 16-code column group (lexicographic) ----
#pragma unroll
        for (int s = 0; s < 2; ++s) {
#pragma unroll
            for (int r = 0; r < 4; ++r) {
                float d = bestd[s][r]; int k = bestk[s][r];
#pragma unroll
                for (int off = 1; off < 16; off <<= 1) {
                    float od = __shfl_xor(d, off, 64);
                    int   ok = __shfl_xor(k, off, 64);
                    if (od < d || (od == d && ok < k)) { d = od; k = ok; }
                }
                if (cl == 0) {
                    int vloc = wid * 128 + it * 32 + s * 16 + cg * 4 + r;
                    size_t o = (size_t)q * NVEC + v0 + vloc;
                    pd[o] = d;
                    pk[o] = (unsigned char)k;
                }
            }
        }
    }
}

// Memory-bound epilogue: thread = vector. Merge 4 quarter-candidates
// (q-ascending, strict < -> global first-min), row-gather codebook (exact
// fp32), coalesced out writes, loss + histogram.
__global__ __launch_bounds__(256) void vq_epilogue(
    const float* __restrict__ x, const float* __restrict__ weight,
    const float* __restrict__ pd, const unsigned char* __restrict__ pk,
    float* __restrict__ out, float* __restrict__ gsq, int* __restrict__ ghist)
{
    __shared__ float lsum[4];
    __shared__ int lhist[K_CODES];
    const int tid = threadIdx.x;
    for (int i = tid; i < K_CODES; i += 256) lhist[i] = 0;
    __syncthreads();

    const int v = blockIdx.x * 256 + tid;
    const int b = v >> 12;
    const int l = v & 4095;

    float bd = pd[v];
    int   kk = pk[v];
#pragma unroll
    for (int q = 1; q < NQ; ++q) {
        float d = pd[(size_t)q * NVEC + v];
        if (d < bd) { bd = d; kk = q * 128 + pk[(size_t)q * NVEC + v]; }
    }
    atomicAdd(&lhist[kk], 1);

    const float* xp = x + (size_t)b * DIM * SEQ + l;
    const float* wr = weight + (size_t)kk * DIM;
    float* op = out + 1 + (size_t)b * DIM * SEQ + l;

    float sq = 0.f;
#pragma unroll
    for (int c = 0; c < DIM; c += 4) {
        float4 wv = *(const float4*)(wr + c);
        float x0 = xp[(size_t)(c + 0) * SEQ];
        float x1 = xp[(size_t)(c + 1) * SEQ];
        float x2 = xp[(size_t)(c + 2) * SEQ];
        float x3 = xp[(size_t)(c + 3) * SEQ];
        float e0 = wv.x - x0, e1 = wv.y - x1, e2 = wv.z - x2, e3 = wv.w - x3;
        sq = fmaf(e0, e0, sq);
        sq = fmaf(e1, e1, sq);
        sq = fmaf(e2, e2, sq);
        sq = fmaf(e3, e3, sq);
        op[(size_t)(c + 0) * SEQ] = wv.x;
        op[(size_t)(c + 1) * SEQ] = wv.y;
        op[(size_t)(c + 2) * SEQ] = wv.z;
        op[(size_t)(c + 3) * SEQ] = wv.w;
    }

#pragma unroll
    for (int off = 32; off; off >>= 1) sq += __shfl_down(sq, off, 64);
    if ((tid & 63) == 0) lsum[tid >> 6] = sq;
    __syncthreads();
    if (tid == 0) {
        float s = lsum[0] + lsum[1] + lsum[2] + lsum[3];
        atomicAdd(gsq, s);
    }
    for (int i = tid; i < K_CODES; i += 256) {
        int cnt = lhist[i];
        if (cnt) atomicAdd(&ghist[i], cnt);
    }
}

__global__ void vq_finalize(const int* __restrict__ hist,
                            const float* __restrict__ gsq,
                            float* __restrict__ out, int out_last)
{
    __shared__ float part[8];
    int t = threadIdx.x;  // 512 threads
    float p = (float)hist[t] * (1.0f / (float)NVEC);
    float term = p * logf(p + 1e-10f);
#pragma unroll
    for (int off = 32; off; off >>= 1) term += __shfl_down(term, off, 64);
    if ((t & 63) == 0) part[t >> 6] = term;
    __syncthreads();
    if (t == 0) {
        float s = 0.f;
#pragma unroll
        for (int i = 0; i < 8; ++i) s += part[i];
        out[out_last] = expf(-s);
        out[0] = 1.25f * gsq[0] / (float)NELEM;
    }
}

extern "C" void kernel_launch(void* const* d_in, const int* in_sizes, int n_in,
                              void* d_out, int out_size, void* d_ws, size_t ws_size,
                              hipStream_t stream) {
    const float* x = (const float*)d_in[0];
    const float* weight = (const float*)d_in[1];
    float* out = (float*)d_out;

    int* ghist = (int*)d_ws;
    float* gsq = (float*)((char*)d_ws + WS_GSQ);
    float* wsq = (float*)((char*)d_ws + WS_WSQ);
    short8* wf = (short8*)((char*)d_ws + WS_WFRAG);
    float* pd = (float*)((char*)d_ws + WS_PD);
    unsigned char* pk = (unsigned char*)((char*)d_ws + WS_PK);

    hipMemsetAsync(d_ws, 0, 2052, stream);

    vq_setup<<<48, 256, 0, stream>>>(weight, wf, wsq);
    vq_argmin<<<NQ * 256, 256, 0, stream>>>(x, wf, wsq, pd, pk);
    vq_epilogue<<<NVEC / 256, 256, 0, stream>>>(x, weight, pd, pk, out, gsq, ghist);
    vq_finalize<<<1, K_CODES, 0, stream>>>(ghist, gsq, out, out_size - 1);
}

// Round 14
// 104.164 us; speedup vs baseline: 6.9187x; 6.9187x over previous
//
#include <hip/hip_runtime.h>

// Problem constants
#define K_CODES 512
#define DIM 80
#define SEQ 4096
#define NVEC 131072
#define NELEM ((size_t)NVEC * DIM)
#define VPW 32                       // vectors per block: 1 wave x 2 A-sets x 16
#define NTILES 32                    // 16-code tiles
#define TILE_BYTES 6144              // 384 short8 per tile

typedef short short8 __attribute__((ext_vector_type(8)));
typedef float f32x4 __attribute__((ext_vector_type(4)));

// ws layout: ghist[512] @0 | gsq @2048 | wsq[512] @4096 | wfrag @8192 (196608 B) | bk @204800
#define WS_GSQ   2048
#define WS_WSQ   4096
#define WS_WFRAG 8192
#define WS_BK    (8192 + 196608)

__device__ __forceinline__ unsigned short f2bf(float f) {
    union { float f; unsigned int u; } c; c.f = f;
    unsigned int r = c.u + 0x7FFFu + ((c.u >> 16) & 1u);   // RNE
    return (unsigned short)(r >> 16);
}
__device__ __forceinline__ float bf2f(unsigned short h) {
    union { float f; unsigned int u; } c; c.u = ((unsigned int)h) << 16;
    return c.f;
}

__device__ __forceinline__ void gload_lds16(const void* g, void* l) {
    __builtin_amdgcn_global_load_lds(
        (const __attribute__((address_space(1))) void*)g,
        (__attribute__((address_space(3))) void*)l, 16, 0, 0);
}

// Fused setup: wfrag (fragment-ordered split codebook) + wsq (row norms).
// wfrag: [t16 0..31][g 0..5][lane 0..63] short8; g<3: hi,ks=g; g>=3: lo,ks=g-3;
//        lane=(cg<<4)|cl; value = w{hi,lo}[code=t16*16+cl][c=ks*32+cg*8 ..+8)
__global__ void vq_setup(const float* __restrict__ weight,
                         short8* __restrict__ wf, float* __restrict__ wsq)
{
    int idx = blockIdx.x * 256 + threadIdx.x;   // 48 blocks -> 12288
    if (blockIdx.x < 2) {
        int k = blockIdx.x * 256 + threadIdx.x;
        const float* w = weight + (size_t)k * DIM;
        float s = 0.f;
#pragma unroll
        for (int c = 0; c < DIM; ++c) s = fmaf(w[c], w[c], s);
        wsq[k] = s;
    }
    int t   = idx / 384;
    int rem = idx - t * 384;
    int g   = rem >> 6, l = rem & 63;
    int cl  = l & 15, cg = l >> 4;
    int ks  = g % 3, h = g / 3;
    int code = t * 16 + cl;
    int c0 = ks * 32 + cg * 8;
    short8 v;
#pragma unroll
    for (int j = 0; j < 8; ++j) {
        int c = c0 + j;
        unsigned short r = 0;
        if (c < DIM) {
            float f = weight[(size_t)code * DIM + c];
            unsigned short hb = f2bf(f);
            r = h ? f2bf(f - bf2f(hb)) : hb;
        }
        v[j] = (short)r;
    }
    wf[idx] = v;
}

// Wave-private distance GEMM + argmin: 1 wave/block, 32 vectors, 512 codes.
// Private double-buffered B tile in LDS; NO barriers anywhere. Per tile:
// vmcnt(6) [own staging t landed, t+1 in flight] -> 12 ds_read_b128 + 1 wsq
// -> lgkmcnt(0) -> issue stage(t+2) into vacated buffer -> 18 MFMA -> fold.
// Register envelope identical to R9 (compiled VGPR=64, no spill).
__global__ __launch_bounds__(64, 3) void vq_argmin(
    const float* __restrict__ x, const short8* __restrict__ wf,
    const float* __restrict__ wsq, int* __restrict__ bk)
{
    __shared__ short8 bbuf[2][384];    // 2 x 6 KB private B tiles
    __shared__ float wsq_lds[K_CODES]; // 2 KB

    const int lane = threadIdx.x;
    const int v0 = blockIdx.x * VPW;
    const int b  = v0 >> 12;
    const int l0 = v0 & 4095;
    const float* xbase = x + (size_t)b * DIM * SEQ + l0;

    const int cg = lane >> 4;          // k-group 0..3
    const int cl = lane & 15;          // A row / B col

    // ---- prologue staging: wsq (2 ops), tile 0 (6 ops) ----
    gload_lds16((const char*)wsq + lane * 16, (char*)wsq_lds + lane * 16);
    gload_lds16((const char*)wsq + 1024 + lane * 16, (char*)wsq_lds + 1024 + lane * 16);
    {
        const char* src = (const char*)wf + lane * 16;
        char* dst = (char*)&bbuf[0][0] + lane * 16;
#pragma unroll
        for (int i = 0; i < 6; ++i) gload_lds16(src + i * 1024, dst + i * 1024);
    }

    // ---- A fragments (2 sets, hi/lo), direct from global ----
    short8 ahi0[3], alo0[3], ahi1[3], alo1[3];
#pragma unroll
    for (int ks = 0; ks < 3; ++ks) {
#pragma unroll
        for (int j = 0; j < 8; ++j) {
            int c = ks * 32 + cg * 8 + j;
            unsigned short h0 = 0, p0 = 0, h1 = 0, p1 = 0;
            if (c < DIM) {
                float f0 = xbase[(size_t)c * SEQ + cl];
                float f1 = xbase[(size_t)c * SEQ + 16 + cl];
                h0 = f2bf(f0); p0 = f2bf(f0 - bf2f(h0));
                h1 = f2bf(f1); p1 = f2bf(f1 - bf2f(h1));
            }
            ahi0[ks][j] = (short)h0; alo0[ks][j] = (short)p0;
            ahi1[ks][j] = (short)h1; alo1[ks][j] = (short)p1;
        }
    }

    // ---- stage tile 1 LAST: in-loop vmcnt(6) then covers wsq+tile0+A too ----
    {
        const char* src = (const char*)wf + TILE_BYTES + lane * 16;
        char* dst = (char*)&bbuf[1][0] + lane * 16;
#pragma unroll
        for (int i = 0; i < 6; ++i) gload_lds16(src + i * 1024, dst + i * 1024);
    }

    float bestd[2][4];
    int   bestk[2][4];
#pragma unroll
    for (int s = 0; s < 2; ++s)
#pragma unroll
        for (int r = 0; r < 4; ++r) { bestd[s][r] = 3.4028235e38f; bestk[s][r] = 0; }

    for (int t = 0; t < NTILES; ++t) {
        // tile t's staging landed (tile t+1's 6 ops may remain in flight)
        if (t + 1 < NTILES) asm volatile("s_waitcnt vmcnt(6)" ::: "memory");
        else                asm volatile("s_waitcnt vmcnt(0)" ::: "memory");
        __builtin_amdgcn_sched_barrier(0);

        const short8* bb = &bbuf[t & 1][0];
        short8 bh0 = bb[lane];
        short8 bh1 = bb[64 + lane];
        short8 bh2 = bb[128 + lane];
        short8 bl0 = bb[192 + lane];
        short8 bl1 = bb[256 + lane];
        short8 bl2 = bb[320 + lane];
        float wv = wsq_lds[t * 16 + cl];
        asm volatile("s_waitcnt lgkmcnt(0)" ::: "memory");   // LDS data in regs
        __builtin_amdgcn_sched_barrier(0);

        // now safe to overwrite this buffer: stage tile t+2 (hides under MFMA)
        if (t + 2 < NTILES) {
            const char* src = (const char*)wf + (size_t)(t + 2) * TILE_BYTES + lane * 16;
            char* dst = (char*)&bbuf[t & 1][0] + lane * 16;
#pragma unroll
            for (int i = 0; i < 6; ++i) gload_lds16(src + i * 1024, dst + i * 1024);
        }
        __builtin_amdgcn_sched_barrier(0);

        f32x4 a00 = {0.f,0.f,0.f,0.f}, a01 = {0.f,0.f,0.f,0.f}, a02 = {0.f,0.f,0.f,0.f};
        f32x4 a10 = {0.f,0.f,0.f,0.f}, a11 = {0.f,0.f,0.f,0.f}, a12 = {0.f,0.f,0.f,0.f};
        __builtin_amdgcn_s_setprio(1);
        // R9-identical per-set sequence: 3 chains (hh -> hl -> lh), sets interleaved
        a00 = __builtin_amdgcn_mfma_f32_16x16x32_bf16(ahi0[0], bh0, a00, 0, 0, 0);
        a01 = __builtin_amdgcn_mfma_f32_16x16x32_bf16(ahi0[1], bh1, a01, 0, 0, 0);
        a02 = __builtin_amdgcn_mfma_f32_16x16x32_bf16(ahi0[2], bh2, a02, 0, 0, 0);
        a10 = __builtin_amdgcn_mfma_f32_16x16x32_bf16(ahi1[0], bh0, a10, 0, 0, 0);
        a11 = __builtin_amdgcn_mfma_f32_16x16x32_bf16(ahi1[1], bh1, a11, 0, 0, 0);
        a12 = __builtin_amdgcn_mfma_f32_16x16x32_bf16(ahi1[2], bh2, a12, 0, 0, 0);
        a00 = __builtin_amdgcn_mfma_f32_16x16x32_bf16(ahi0[0], bl0, a00, 0, 0, 0);
        a01 = __builtin_amdgcn_mfma_f32_16x16x32_bf16(ahi0[1], bl1, a01, 0, 0, 0);
        a02 = __builtin_amdgcn_mfma_f32_16x16x32_bf16(ahi0[2], bl2, a02, 0, 0, 0);
        a10 = __builtin_amdgcn_mfma_f32_16x16x32_bf16(ahi1[0], bl0, a10, 0, 0, 0);
        a11 = __builtin_amdgcn_mfma_f32_16x16x32_bf16(ahi1[1], bl1, a11, 0, 0, 0);
        a12 = __builtin_amdgcn_mfma_f32_16x16x32_bf16(ahi1[2], bl2, a12, 0, 0, 0);
        a00 = __builtin_amdgcn_mfma_f32_16x16x32_bf16(alo0[0], bh0, a00, 0, 0, 0);
        a01 = __builtin_amdgcn_mfma_f32_16x16x32_bf16(alo0[1], bh1, a01, 0, 0, 0);
        a02 = __builtin_amdgcn_mfma_f32_16x16x32_bf16(alo0[2], bh2, a02, 0, 0, 0);
        a10 = __builtin_amdgcn_mfma_f32_16x16x32_bf16(alo1[0], bh0, a10, 0, 0, 0);
        a11 = __builtin_amdgcn_mfma_f32_16x16x32_bf16(alo1[1], bh1, a11, 0, 0, 0);
        a12 = __builtin_amdgcn_mfma_f32_16x16x32_bf16(alo1[2], bh2, a12, 0, 0, 0);
        __builtin_amdgcn_s_setprio(0);

        const int code = t * 16 + cl;
#pragma unroll
        for (int r = 0; r < 4; ++r) {
            float d0 = a00[r] + a01[r] + a02[r];
            float q0 = fmaf(-2.f, d0, wv);
            if (q0 < bestd[0][r]) { bestd[0][r] = q0; bestk[0][r] = code; }
            float d1 = a10[r] + a11[r] + a12[r];
            float q1 = fmaf(-2.f, d1, wv);
            if (q1 < bestd[1][r]) { bestd[1][r] = q1; bestk[1][r] = code; }
        }
    }

    // ---- cross-lane argmin over 16-code column groups (lexicographic) ----
#pragma unroll
    for (int s = 0; s < 2; ++s) {
#pragma unroll
        for (int r = 0; r < 4; ++r) {
            float d = bestd[s][r]; int k = bestk[s][r];
#pragma unroll
            for (int off = 1; off < 16; off <<= 1) {
                float od = __shfl_xor(d, off, 64);
                int   ok = __shfl_xor(k, off, 64);
                if (od < d || (od == d && ok < k)) { d = od; k = ok; }
            }
            if (cl == 0) {
                int vloc = s * 16 + cg * 4 + r;      // D row = (lane>>4)*4 + reg
                bk[v0 + vloc] = k;
            }
        }
    }
}

// Memory-bound epilogue: thread = vector. Row-gather codebook (exact fp32),
// coalesced x reads / out writes, loss + histogram.
__global__ __launch_bounds__(256) void vq_epilogue(
    const float* __restrict__ x, const float* __restrict__ weight,
    const int* __restrict__ bk, float* __restrict__ out,
    float* __restrict__ gsq, int* __restrict__ ghist)
{
    __shared__ float lsum[4];
    __shared__ int lhist[K_CODES];
    const int tid = threadIdx.x;
    for (int i = tid; i < K_CODES; i += 256) lhist[i] = 0;
    __syncthreads();

    const int v = blockIdx.x * 256 + tid;
    const int b = v >> 12;
    const int l = v & 4095;
    const int kk = bk[v];
    atomicAdd(&lhist[kk], 1);

    const float* xp = x + (size_t)b * DIM * SEQ + l;
    const float* wr = weight + (size_t)kk * DIM;
    float* op = out + 1 + (size_t)b * DIM * SEQ + l;

    float sq = 0.f;
#pragma unroll
    for (int c = 0; c < DIM; c += 4) {
        float4 wv = *(const float4*)(wr + c);
        float x0 = xp[(size_t)(c + 0) * SEQ];
        float x1 = xp[(size_t)(c + 1) * SEQ];
        float x2 = xp[(size_t)(c + 2) * SEQ];
        float x3 = xp[(size_t)(c + 3) * SEQ];
        float e0 = wv.x - x0, e1 = wv.y - x1, e2 = wv.z - x2, e3 = wv.w - x3;
        sq = fmaf(e0, e0, sq);
        sq = fmaf(e1, e1, sq);
        sq = fmaf(e2, e2, sq);
        sq = fmaf(e3, e3, sq);
        op[(size_t)(c + 0) * SEQ] = wv.x;
        op[(size_t)(c + 1) * SEQ] = wv.y;
        op[(size_t)(c + 2) * SEQ] = wv.z;
        op[(size_t)(c + 3) * SEQ] = wv.w;
    }

#pragma unroll
    for (int off = 32; off; off >>= 1) sq += __shfl_down(sq, off, 64);
    if ((tid & 63) == 0) lsum[tid >> 6] = sq;
    __syncthreads();
    if (tid == 0) {
        float s = lsum[0] + lsum[1] + lsum[2] + lsum[3];
        atomicAdd(gsq, s);
    }
    for (int i = tid; i < K_CODES; i += 256) {
        int cnt = lhist[i];
        if (cnt) atomicAdd(&ghist[i], cnt);
    }
}

__global__ void vq_finalize(const int* __restrict__ hist,
                            const float* __restrict__ gsq,
                            float* __restrict__ out, int out_last)
{
    __shared__ float part[8];
    int t = threadIdx.x;  // 512 threads
    float p = (float)hist[t] * (1.0f / (float)NVEC);
    float term = p * logf(p + 1e-10f);
#pragma unroll
    for (int off = 32; off; off >>= 1) term += __shfl_down(term, off, 64);
    if ((t & 63) == 0) part[t >> 6] = term;
    __syncthreads();
    if (t == 0) {
        float s = 0.f;
#pragma unroll
        for (int i = 0; i < 8; ++i) s += part[i];
        out[out_last] = expf(-s);
        out[0] = 1.25f * gsq[0] / (float)NELEM;
    }
}

extern "C" void kernel_launch(void* const* d_in, const int* in_sizes, int n_in,
                              void* d_out, int out_size, void* d_ws, size_t ws_size,
                              hipStream_t stream) {
    const float* x = (const float*)d_in[0];
    const float* weight = (const float*)d_in[1];
    float* out = (float*)d_out;

    int* ghist = (int*)d_ws;
    float* gsq = (float*)((char*)d_ws + WS_GSQ);
    float* wsq = (float*)((char*)d_ws + WS_WSQ);
    short8* wf = (short8*)((char*)d_ws + WS_WFRAG);
    int* bk = (int*)((char*)d_ws + WS_BK);

    hipMemsetAsync(d_ws, 0, 2052, stream);

    vq_setup<<<48, 256, 0, stream>>>(weight, wf, wsq);
    vq_argmin<<<NVEC / VPW, 64, 0, stream>>>(x, wf, wsq, bk);
    vq_epilogue<<<NVEC / 256, 256, 0, stream>>>(x, weight, bk, out, gsq, ghist);
    vq_finalize<<<1, K_CODES, 0, stream>>>(ghist, gsq, out, out_size - 1);
}